// Round 9
// baseline (65.169 us; speedup 1.0000x reference)
//
#include <hip/hip_runtime.h>
#include <math.h>
#include <stdint.h>

#define NB1    4096
#define NBTOT  8192
#define NFD    128
#define NSLICE 16                // column slices
#define ECOLS  512               // columns per block
#define BROWS  128
#define BCOLS  64
#define NTILES (ECOLS / BCOLS)   // 8

typedef __attribute__((ext_vector_type(8))) _Float16 f16x8;
typedef __attribute__((ext_vector_type(4))) float f32x4;
typedef _Float16 f16;

// async 16B global->LDS; lds base wave-uniform, HW adds lane*16
__device__ __forceinline__ void gl16(const f16* g, char* l) {
    __builtin_amdgcn_global_load_lds(
        (const __attribute__((address_space(1))) unsigned int*)g,
        (__attribute__((address_space(3))) unsigned int*)l,
        16, 0, 0);
}

// ---------------------------------------------------------------------------
// Kernel 1: row L2-normalize -> fp16. One wave per row. Block 0 also zeroes
// the tail counters (rtcnt[64], gcnt) used by simstat's fused loss.
// ---------------------------------------------------------------------------
__global__ void norm_k(const float* __restrict__ f1, const float* __restrict__ f2,
                       f16* __restrict__ nfh, int* __restrict__ cnts) {
    if (blockIdx.x == 0 && threadIdx.x < 65) cnts[threadIdx.x] = 0;
    const int w = threadIdx.x >> 6, lane = threadIdx.x & 63;
    const int row = blockIdx.x * 4 + w;
    const float* src = (row < NB1) ? (f1 + (size_t)row * NFD)
                                   : (f2 + (size_t)(row - NB1) * NFD);
    const float2 v = *reinterpret_cast<const float2*>(src + 2 * lane);
    float s = v.x * v.x + v.y * v.y;
#pragma unroll
    for (int m = 32; m >= 1; m >>= 1) s += __shfl_xor(s, m, 64);
    const float inv = 1.0f / fmaxf(sqrtf(s), 1e-12f);
    const f16 h0 = (f16)(v.x * inv);
    const f16 h1 = (f16)(v.y * inv);
    const unsigned pack = (unsigned)__builtin_bit_cast(unsigned short, h0) |
                          ((unsigned)__builtin_bit_cast(unsigned short, h1) << 16);
    ((unsigned*)(nfh + (size_t)row * NFD))[lane] = pack;
}

// ---------------------------------------------------------------------------
// Kernel 2: fp16 MFMA sim-stats + fused loss tail.
// Grid (16 col-slices, 64 row-tiles) = 1024 blocks; 256 thr = 4 waves in a
// 2x2 wave grid: wave w -> rows 64*(w>>1)+ (fa=4), cols 32*(w&1)+ (fb=2).
// __launch_bounds__(256,3) -> 3 blocks = 12 waves/CU (latency hiding).
// A-frags register-resident (64 VGPR, tile-invariant). LDS = B dbuf 2x16KB.
// 4-bit XOR swizzle on 16B slots; staged via global_load_lds (pre-swizzled
// source; measured 0 bank conflicts with this pattern).
// Tail: 16th finisher per rt computes that rt's 128 row-losses; 64th
// rt-finisher reduces 64 partials -> out. Deterministic (fixed values/order).
// ---------------------------------------------------------------------------
__global__ __launch_bounds__(256, 3) void simstat_mfma(const f16* __restrict__ nfh,
                                                       float* __restrict__ posp,
                                                       float* __restrict__ sexpp,
                                                       int* __restrict__ rtcnt,
                                                       int* __restrict__ gcnt,
                                                       float* __restrict__ lossPartial,
                                                       float* __restrict__ out) {
    extern __shared__ __align__(16) char smem[];   // 32768 = 2 x 16KB

    const int e    = blockIdx.x;          // column slice 0..15
    const int rt   = blockIdx.y;
    const int row0 = rt * BROWS;
    const int col0e = e * ECOLS;
    const bool same = ((row0 >= NB1) == (e >= 8));
    const int p = e & 7;

    const int t    = threadIdx.x;
    const int w    = t >> 6;
    const int lane = t & 63;
    const int lr   = lane & 15;
    const int lg   = lane >> 4;
    const int rowbase = 64 * (w >> 1);    // 2 row-stripes of 64
    const int colbase = 32 * (w & 1);     // 2 col-stripes of 32

    // ---- stage mapping (loop-invariant): 4 waves x 4KB = 16KB tile ----
    int goffs[4], dbase[4];
#pragma unroll
    for (int i = 0; i < 4; ++i) {
        const int base = w * 4096 + i * 1024;
        const int d    = base + lane * 16;
        const int sr   = d >> 8;            // dest row 0..63
        const int slot = (d >> 4) & 15;
        const int kc   = slot ^ (sr & 15);  // source k-chunk (involution)
        goffs[i] = sr * NFD + kc * 8;
        dbase[i] = base;
    }
    // read offsets (row&15 == lr since colbase,16*fb are multiples of 16)
    int rbo[2], koff[4];
#pragma unroll
    for (int fb = 0; fb < 2; ++fb) rbo[fb] = (colbase + 16 * fb + lr) * 256;
#pragma unroll
    for (int ks = 0; ks < 4; ++ks) koff[ks] = (((ks << 2) + lg) ^ lr) << 4;

    // ---- stage B tile 0 (async) ----
    {
        const f16* g0 = nfh + (size_t)col0e * NFD;
#pragma unroll
        for (int i = 0; i < 4; ++i) gl16(g0 + goffs[i], smem + dbase[i]);
    }

    // ---- A fragments -> registers (tile-invariant): 16 x 4 VGPR ----
    f16x8 ah[4][4];
#pragma unroll
    for (int ks = 0; ks < 4; ++ks)
#pragma unroll
        for (int fa = 0; fa < 4; ++fa) {
            const size_t off = (size_t)(row0 + rowbase + 16 * fa + lr) * NFD + 32 * ks + 8 * lg;
            ah[ks][fa] = *reinterpret_cast<const f16x8*>(nfh + off);
        }

    __syncthreads();   // tile0 + A loads complete

    float stat[4][4];
#pragma unroll
    for (int fa = 0; fa < 4; ++fa)
#pragma unroll
        for (int r = 0; r < 4; ++r) stat[fa][r] = same ? -3.0e38f : 0.0f;
    const float K2 = 1.44269504089f / 0.07f;   // log2(e)/tau
    const float invtau = 1.0f / 0.07f;

#pragma unroll 1
    for (int tile = 0; tile < NTILES; ++tile) {
        const char* bufB = smem + (tile & 1) * 16384;

        // issue next-tile stage early (lands during compute, drained at barrier)
        if (tile + 1 < NTILES) {
            char* nb = smem + ((tile + 1) & 1) * 16384;
            const f16* gn = nfh + (size_t)(col0e + (tile + 1) * BCOLS) * NFD;
#pragma unroll
            for (int i = 0; i < 4; ++i) gl16(gn + goffs[i], nb + dbase[i]);
        }

        f32x4 acc[4][2];
#pragma unroll
        for (int fa = 0; fa < 4; ++fa)
#pragma unroll
            for (int fb = 0; fb < 2; ++fb) {
                f32x4 z = {0.0f, 0.0f, 0.0f, 0.0f};
                acc[fa][fb] = z;
            }

#pragma unroll
        for (int ks = 0; ks < 4; ++ks) {
            f16x8 b[2];
#pragma unroll
            for (int fb = 0; fb < 2; ++fb)
                b[fb] = *(const f16x8*)(bufB + rbo[fb] + koff[ks]);
            __builtin_amdgcn_s_setprio(1);
#pragma unroll
            for (int fb = 0; fb < 2; ++fb)
#pragma unroll
                for (int fa = 0; fa < 4; ++fa)
                    acc[fa][fb] = __builtin_amdgcn_mfma_f32_16x16x32_f16(ah[ks][fa], b[fb], acc[fa][fb], 0, 0, 0);
            __builtin_amdgcn_s_setprio(0);
        }

        // fold acc into stat; C/D: col=lane&15, row=4*lg+reg (m89-verified)
        if (same) {
            const int col0 = col0e + tile * BCOLS;
#pragma unroll
            for (int fa = 0; fa < 4; ++fa)
#pragma unroll
                for (int fb = 0; fb < 2; ++fb)
#pragma unroll
                    for (int r = 0; r < 4; ++r) {
                        const int grow = row0 + rowbase + 16 * fa + 4 * lg + r;
                        const int gcol = col0 + colbase + 16 * fb + lr;
                        stat[fa][r] = (grow == gcol) ? stat[fa][r]
                                                     : fmaxf(stat[fa][r], acc[fa][fb][r]);
                    }
        } else {
#pragma unroll
            for (int fa = 0; fa < 4; ++fa)
#pragma unroll
                for (int fb = 0; fb < 2; ++fb)
#pragma unroll
                    for (int r = 0; r < 4; ++r)
                        stat[fa][r] += exp2f(acc[fa][fb][r] * K2);
        }

        __syncthreads();
    }

    // reduce over the 16 cols held across lr (lane bits 0..3)
#pragma unroll
    for (int m = 1; m <= 8; m <<= 1) {
#pragma unroll
        for (int fa = 0; fa < 4; ++fa)
#pragma unroll
            for (int r = 0; r < 4; ++r) {
                const float o = __shfl_xor(stat[fa][r], m, 64);
                stat[fa][r] = same ? fmaxf(stat[fa][r], o) : (stat[fa][r] + o);
            }
    }

    // combine the two col-stripe waves per row via LDS scratch
    float* scratch = (float*)smem;
    if (lr == 0) {
#pragma unroll
        for (int fa = 0; fa < 4; ++fa)
#pragma unroll
            for (int r = 0; r < 4; ++r) {
                const int rl = rowbase + 16 * fa + 4 * lg + r;
                scratch[(w & 1) * 128 + rl] = stat[fa][r];
            }
    }
    __syncthreads();
    if (t < 128) {
        const float v0 = scratch[t];
        const float v1 = scratch[128 + t];
        const float v = same ? fmaxf(v0, v1) * invtau : (v0 + v1);
        (same ? posp : sexpp)[(size_t)p * NBTOT + row0 + t] = v;
    }
    __syncthreads();

    // ---- fused loss tail: last-finisher-per-rt pattern ----
    int* flags = (int*)smem;
    if (t == 0) {
        __threadfence();                       // release our posp/sexpp writes
        const int old = atomicAdd(&rtcnt[rt], 1);
        const int last = (old == NSLICE - 1);
        if (last) __threadfence();             // acquire others' writes
        flags[0] = last;
    }
    __syncthreads();
    if (!flags[0]) return;

    float* scf = (float*)smem + 8;
    float l = 0.0f;
    if (t < 128) {
        const int r = row0 + t;
        float pv = -3.0e38f, se = 0.0f;
#pragma unroll
        for (int j = 0; j < 8; ++j) {
            pv = fmaxf(pv, posp[(size_t)j * NBTOT + r]);
            se += sexpp[(size_t)j * NBTOT + r];
        }
        l = log1pf(se * __expf(-pv));
    }
#pragma unroll
    for (int m = 32; m >= 1; m >>= 1) l += __shfl_xor(l, m, 64);
    if (t < 128 && lane == 0) scf[w] = l;     // waves 0,1
    __syncthreads();
    if (t == 0) {
        lossPartial[rt] = scf[0] + scf[1];
        __threadfence();
        const int old = atomicAdd(gcnt, 1);
        const int lastg = (old == 63);
        if (lastg) __threadfence();
        flags[1] = lastg;
    }
    __syncthreads();
    if (!flags[1]) return;

    if (t < 64) {
        float s = lossPartial[t];
#pragma unroll
        for (int m = 32; m >= 1; m >>= 1) s += __shfl_xor(s, m, 64);
        if (t == 0) out[0] = s / (float)NBTOT;
    }
}

// ---------------------------------------------------------------------------
extern "C" void kernel_launch(void* const* d_in, const int* in_sizes, int n_in,
                              void* d_out, int out_size, void* d_ws, size_t ws_size,
                              hipStream_t stream) {
    const float* f1 = (const float*)d_in[0];
    const float* f2 = (const float*)d_in[1];

    f16*   nfh         = (f16*)d_ws;                          // 2 MB
    float* posp        = (float*)(nfh + (size_t)NBTOT * NFD); // 8*8192 f32
    float* sexpp       = posp + 8 * NBTOT;                    // 8*8192 f32
    float* lossPartial = sexpp + 8 * NBTOT;                   // 64 f32
    int*   cnts        = (int*)(lossPartial + 64);            // rtcnt[64] + gcnt

    (void)hipFuncSetAttribute(reinterpret_cast<const void*>(simstat_mfma),
                              hipFuncAttributeMaxDynamicSharedMemorySize, 32768);

    norm_k<<<NBTOT / 4, 256, 0, stream>>>(f1, f2, nfh, cnts);
    simstat_mfma<<<dim3(NSLICE, 64), 256, 32768, stream>>>(
        nfh, posp, sexpp, cnts, cnts + 64, lossPartial, (float*)d_out);
}

// Round 11
// 55.091 us; speedup vs baseline: 1.1829x; 1.1829x over previous
//
#include <hip/hip_runtime.h>
#include <math.h>
#include <stdint.h>

#define NB1    4096
#define NBTOT  8192
#define NFD    128
#define NT     64            // 128-row tiles per side
#define NPAIR  2080          // NT*(NT+1)/2 triangle tile-pairs
#define NSL    32            // partial slices per class

typedef __attribute__((ext_vector_type(8))) _Float16 f16x8;
typedef __attribute__((ext_vector_type(4))) float f32x4;
typedef _Float16 f16;

// async 16B global->LDS; lds base wave-uniform, HW adds lane*16
__device__ __forceinline__ void gl16(const f16* g, char* l) {
    __builtin_amdgcn_global_load_lds(
        (const __attribute__((address_space(1))) unsigned int*)g,
        (__attribute__((address_space(3))) unsigned int*)l,
        16, 0, 0);
}

// ---------------------------------------------------------------------------
// Kernel 1: row L2-normalize -> fp16 (fp16 dot err ~4.9e-4 -> loss err ~0.015
// << 0.0925 threshold; validated R8). One wave per row.
// ---------------------------------------------------------------------------
__global__ void norm_k(const float* __restrict__ f1, const float* __restrict__ f2,
                       f16* __restrict__ nfh) {
    const int w = threadIdx.x >> 6, lane = threadIdx.x & 63;
    const int row = blockIdx.x * 4 + w;
    const float* src = (row < NB1) ? (f1 + (size_t)row * NFD)
                                   : (f2 + (size_t)(row - NB1) * NFD);
    const float2 v = *reinterpret_cast<const float2*>(src + 2 * lane);
    float s = v.x * v.x + v.y * v.y;
#pragma unroll
    for (int m = 32; m >= 1; m >>= 1) s += __shfl_xor(s, m, 64);
    const float inv = 1.0f / fmaxf(sqrtf(s), 1e-12f);
    const f16 h0 = (f16)(v.x * inv);
    const f16 h1 = (f16)(v.y * inv);
    const unsigned pack = (unsigned)__builtin_bit_cast(unsigned short, h0) |
                          ((unsigned)__builtin_bit_cast(unsigned short, h1) << 16);
    ((unsigned*)(nfh + (size_t)row * NFD))[lane] = pack;
}

// ---------------------------------------------------------------------------
// Kernel 2: symmetric-triangle MFMA sim-stats. 2080 blocks, one 128x128
// tile-pair (rt<=ct) each; sim computed ONCE per unordered pair, folded into
// row-stats (rows of rt, slice ct&31) AND col-stats (rows of ct, slice rt&31).
// 256 thr = 4 waves, 2x2 wave grid (fa=4, fb=4). A-frags in regs; B staged
// to 32KB LDS via global_load_lds w/ 4-bit XOR swizzle (R8-proven, 0 bank
// conflicts). ks ping-pong pipeline + setprio (R8-proven). No atomics/fences.
// ---------------------------------------------------------------------------
__global__ __launch_bounds__(256, 2) void simstat_tri(const f16* __restrict__ nfh,
                                                      float* __restrict__ posp,
                                                      float* __restrict__ sexpp) {
    __shared__ __align__(16) char smem[32768];

    // triangle decode: offset(rt) = rt*(129-rt)/2 (always even product)
    const int bid = blockIdx.x;
    int rt = (int)((129.0 - sqrt(16641.0 - 8.0 * (double)bid)) * 0.5);
    while ((rt + 1) * (129 - (rt + 1)) / 2 <= bid) ++rt;
    while (rt * (129 - rt) / 2 > bid) --rt;
    const int ct = rt + (bid - rt * (129 - rt) / 2);

    const int row0 = rt * 128;
    const int col0 = ct * 128;
    const bool same = ((rt >= NSL) == (ct >= NSL));
    const bool diag = (rt == ct);

    const int t    = threadIdx.x;
    const int w    = t >> 6;
    const int lane = t & 63;
    const int lr   = lane & 15;
    const int lg   = lane >> 4;
    const int rowbase = 64 * (w >> 1);
    const int colbase = 64 * (w & 1);

    // ---- stage B tile (rows col0..col0+127) -> LDS, async ----
    {
        const f16* g0 = nfh + (size_t)col0 * NFD;
#pragma unroll
        for (int i = 0; i < 8; ++i) {
            const int base = w * 8192 + i * 1024;
            const int d    = base + lane * 16;
            const int sr   = d >> 8;            // dest row 0..127
            const int slot = (d >> 4) & 15;
            const int kc   = slot ^ (sr & 15);  // source k-chunk (involution)
            gl16(g0 + sr * NFD + kc * 8, smem + base);
        }
    }

    // read offsets (row&15 == lr: colbase, 16*fb are multiples of 16)
    int rbo[4], koff[4];
#pragma unroll
    for (int fb = 0; fb < 4; ++fb) rbo[fb] = (colbase + 16 * fb + lr) * 256;
#pragma unroll
    for (int ks = 0; ks < 4; ++ks) koff[ks] = (((ks << 2) + lg) ^ lr) << 4;

    // ---- A fragments -> registers ----
    f16x8 ah[4][4];
#pragma unroll
    for (int ks = 0; ks < 4; ++ks)
#pragma unroll
        for (int fa = 0; fa < 4; ++fa) {
            const size_t off = (size_t)(row0 + rowbase + 16 * fa + lr) * NFD + 32 * ks + 8 * lg;
            ah[ks][fa] = *reinterpret_cast<const f16x8*>(nfh + off);
        }

    __syncthreads();   // stage + A loads complete

    f32x4 acc[4][4];
#pragma unroll
    for (int fa = 0; fa < 4; ++fa)
#pragma unroll
        for (int fb = 0; fb < 4; ++fb) {
            f32x4 z = {0.0f, 0.0f, 0.0f, 0.0f};
            acc[fa][fb] = z;
        }

#define LOADB(ks_, B_)                                                        \
    {                                                                         \
        _Pragma("unroll")                                                     \
        for (int fb = 0; fb < 4; ++fb)                                        \
            B_[fb] = *(const f16x8*)(smem + rbo[fb] + koff[ks_]);             \
    }
#define MFMAS(ks_, B_)                                                        \
    {                                                                         \
        __builtin_amdgcn_s_setprio(1);                                        \
        _Pragma("unroll")                                                     \
        for (int fb = 0; fb < 4; ++fb)                                        \
            _Pragma("unroll")                                                 \
            for (int fa = 0; fa < 4; ++fa)                                    \
                acc[fa][fb] = __builtin_amdgcn_mfma_f32_16x16x32_f16(ah[ks_][fa], B_[fb], acc[fa][fb], 0, 0, 0); \
        __builtin_amdgcn_s_setprio(0);                                        \
    }

    {
        f16x8 b0[4], b1[4];
        LOADB(0, b0);
        LOADB(1, b1);
        MFMAS(0, b0);
        LOADB(2, b0);
        MFMAS(1, b1);
        LOADB(3, b1);
        MFMAS(2, b0);
        MFMAS(3, b1);
    }
#undef LOADB
#undef MFMAS

    // ---- dual fold; C/D: col=lane&15, row=4*lg+reg (m89-verified) ----
    const float K2 = 1.44269504089f / 0.07f;   // log2(e)/tau
    const float invtau = 1.0f / 0.07f;
    float rstat[4][4];   // rows: [fa][r]
    float cstat[4];      // cols: [fb]
#pragma unroll
    for (int fa = 0; fa < 4; ++fa)
#pragma unroll
        for (int r = 0; r < 4; ++r) rstat[fa][r] = same ? -3.0e38f : 0.0f;
#pragma unroll
    for (int fb = 0; fb < 4; ++fb) cstat[fb] = same ? -3.0e38f : 0.0f;

    if (same) {
#pragma unroll
        for (int fa = 0; fa < 4; ++fa)
#pragma unroll
            for (int fb = 0; fb < 4; ++fb)
#pragma unroll
                for (int r = 0; r < 4; ++r) {
                    const float v = acc[fa][fb][r];
                    if (diag) {
                        const int grow = rowbase + 16 * fa + 4 * lg + r;
                        const int gcol = colbase + 16 * fb + lr;
                        if (grow != gcol) rstat[fa][r] = fmaxf(rstat[fa][r], v);
                        // col-stats unused for diag (skipped at write)
                    } else {
                        rstat[fa][r] = fmaxf(rstat[fa][r], v);
                        cstat[fb]    = fmaxf(cstat[fb], v);
                    }
                }
    } else {
#pragma unroll
        for (int fa = 0; fa < 4; ++fa)
#pragma unroll
            for (int fb = 0; fb < 4; ++fb)
#pragma unroll
                for (int r = 0; r < 4; ++r) {
                    const float e = exp2f(acc[fa][fb][r] * K2);  // exp once
                    rstat[fa][r] += e;
                    cstat[fb]    += e;
                }
    }

    // row-stats: reduce over cols -> shfl over lr bits
#pragma unroll
    for (int m = 1; m <= 8; m <<= 1)
#pragma unroll
        for (int fa = 0; fa < 4; ++fa)
#pragma unroll
            for (int r = 0; r < 4; ++r) {
                const float o = __shfl_xor(rstat[fa][r], m, 64);
                rstat[fa][r] = same ? fmaxf(rstat[fa][r], o) : (rstat[fa][r] + o);
            }
    // col-stats: reduce over rows -> shfl over lg bits
#pragma unroll
    for (int m = 16; m <= 32; m <<= 1)
#pragma unroll
        for (int fb = 0; fb < 4; ++fb) {
            const float o = __shfl_xor(cstat[fb], m, 64);
            cstat[fb] = same ? fmaxf(cstat[fb], o) : (cstat[fb] + o);
        }

    __syncthreads();   // done with B buffer; reuse smem as scratch
    float* scr = (float*)smem;      // [0..255] rows, [256..511] cols
    if (lr == 0) {
#pragma unroll
        for (int fa = 0; fa < 4; ++fa)
#pragma unroll
            for (int r = 0; r < 4; ++r)
                scr[(w & 1) * 128 + rowbase + 16 * fa + 4 * lg + r] = rstat[fa][r];
    }
    if (lg == 0) {
#pragma unroll
        for (int fb = 0; fb < 4; ++fb)
            scr[256 + (w >> 1) * 128 + colbase + 16 * fb + lr] = cstat[fb];
    }
    __syncthreads();

    if (t < 128) {
        // rows of rt, partial slice = ct&31
        const float a = scr[t], b = scr[128 + t];
        const float v = same ? fmaxf(a, b) * invtau : (a + b);
        (same ? posp : sexpp)[(size_t)(ct & 31) * NBTOT + row0 + t] = v;
    } else if (!diag) {
        // rows (cols) of ct, partial slice = rt&31
        const int c = t - 128;
        const float a = scr[256 + c], b = scr[384 + c];
        const float v = same ? fmaxf(a, b) * invtau : (a + b);
        (same ? posp : sexpp)[(size_t)(rt & 31) * NBTOT + col0 + c] = v;
    }
}

// ---------------------------------------------------------------------------
// Kernel 3a: per-row loss partials, 32 blocks. loss_i = log1p(S*exp(-pos))
// ---------------------------------------------------------------------------
__global__ void loss_part(const float* __restrict__ posp, const float* __restrict__ sexpp,
                          float* __restrict__ partial) {
    const int i = blockIdx.x * 256 + threadIdx.x;
    float pv = -3.0e38f, se = 0.0f;
#pragma unroll
    for (int s = 0; s < NSL; ++s) {
        pv = fmaxf(pv, posp[(size_t)s * NBTOT + i]);
        se += sexpp[(size_t)s * NBTOT + i];
    }
    float l = log1pf(se * __expf(-pv));
#pragma unroll
    for (int m = 32; m >= 1; m >>= 1) l += __shfl_xor(l, m, 64);
    __shared__ float part[4];
    if ((threadIdx.x & 63) == 0) part[threadIdx.x >> 6] = l;
    __syncthreads();
    if (threadIdx.x == 0)
        partial[blockIdx.x] = part[0] + part[1] + part[2] + part[3];
}

// Kernel 3b: final combine (1 wave).
__global__ void loss_final(const float* __restrict__ partial, float* __restrict__ out) {
    const int t = threadIdx.x;
    float s = (t < 32) ? partial[t] : 0.0f;
#pragma unroll
    for (int m = 32; m >= 1; m >>= 1) s += __shfl_xor(s, m, 64);
    if (t == 0) out[0] = s / (float)NBTOT;
}

// ---------------------------------------------------------------------------
extern "C" void kernel_launch(void* const* d_in, const int* in_sizes, int n_in,
                              void* d_out, int out_size, void* d_ws, size_t ws_size,
                              hipStream_t stream) {
    const float* f1 = (const float*)d_in[0];
    const float* f2 = (const float*)d_in[1];

    f16*   nfh     = (f16*)d_ws;                          // 2 MB
    float* posp    = (float*)(nfh + (size_t)NBTOT * NFD); // 32*8192 f32 = 1 MB
    float* sexpp   = posp + (size_t)NSL * NBTOT;          // 1 MB
    float* partial = sexpp + (size_t)NSL * NBTOT;         // 32 f32

    norm_k<<<NBTOT / 4, 256, 0, stream>>>(f1, f2, nfh);
    simstat_tri<<<NPAIR, 256, 0, stream>>>(nfh, posp, sexpp);
    loss_part<<<NBTOT / 256, 256, 0, stream>>>(posp, sexpp, partial);
    loss_final<<<1, 64, 0, stream>>>(partial, (float*)d_out);
}

// Round 12
// 53.773 us; speedup vs baseline: 1.2119x; 1.0245x over previous
//
#include <hip/hip_runtime.h>
#include <math.h>
#include <stdint.h>

#define NB1    4096
#define NBTOT  8192
#define NFD    128
#define NPAIR  2080          // 64*(64+1)/2 triangle tile-pairs (128-row tiles)
#define PPB    4             // pairs per block
#define NBLK   (NPAIR / PPB) // 520 blocks, exact
#define NSL    64            // partial slices per class (w-split doubled)

typedef __attribute__((ext_vector_type(8))) _Float16 f16x8;
typedef __attribute__((ext_vector_type(4))) float f32x4;
typedef _Float16 f16;

// async 16B global->LDS; lds base wave-uniform, HW adds lane*16
__device__ __forceinline__ void gl16(const f16* g, char* l) {
    __builtin_amdgcn_global_load_lds(
        (const __attribute__((address_space(1))) unsigned int*)g,
        (__attribute__((address_space(3))) unsigned int*)l,
        16, 0, 0);
}

// triangle decode: offset(rt) = rt*(129-rt)/2
__device__ __forceinline__ void decode_pair(int idx, int& rt_, int& ct_) {
    int r = (int)((129.0 - sqrt(16641.0 - 8.0 * (double)idx)) * 0.5);
    while ((r + 1) * (129 - (r + 1)) / 2 <= idx) ++r;
    while (r * (129 - r) / 2 > idx) --r;
    rt_ = r;
    ct_ = r + (idx - r * (129 - r) / 2);
}

// ---------------------------------------------------------------------------
// Kernel 1: row L2-normalize -> fp16 (validated R8: loss err ~0.015 << 0.0925)
// ---------------------------------------------------------------------------
__global__ void norm_k(const float* __restrict__ f1, const float* __restrict__ f2,
                       f16* __restrict__ nfh) {
    const int w = threadIdx.x >> 6, lane = threadIdx.x & 63;
    const int row = blockIdx.x * 4 + w;
    const float* src = (row < NB1) ? (f1 + (size_t)row * NFD)
                                   : (f2 + (size_t)(row - NB1) * NFD);
    const float2 v = *reinterpret_cast<const float2*>(src + 2 * lane);
    float s = v.x * v.x + v.y * v.y;
#pragma unroll
    for (int m = 32; m >= 1; m >>= 1) s += __shfl_xor(s, m, 64);
    const float inv = 1.0f / fmaxf(sqrtf(s), 1e-12f);
    const f16 h0 = (f16)(v.x * inv);
    const f16 h1 = (f16)(v.y * inv);
    const unsigned pack = (unsigned)__builtin_bit_cast(unsigned short, h0) |
                          ((unsigned)__builtin_bit_cast(unsigned short, h1) << 16);
    ((unsigned*)(nfh + (size_t)row * NFD))[lane] = pack;
}

// ---------------------------------------------------------------------------
// Kernel 2: triangle MFMA sim-stats, 4 pairs/block (R8-style amortization).
// 520 blocks = ~2/CU; 256 thr = 4 waves, 2x2 wave grid (fa=4, fb=4).
// A-frags in regs, reloaded only on rt change (A-loads issued BEFORE next-B
// stage so vmcnt wait for A doesn't drain staging). B dbuf 2x32KB LDS, 4-bit
// XOR swizzle via pre-swizzled global_load_lds source (R8-proven, 0 confl).
// Per-pair epilogue: direct global writes, slice 2*(ct&31)+(w&1) for rows of
// rt, slice 2*(rt&31)+(w>>1) for cols (rows of ct); diag col-writes skipped.
// Coverage: each (slice,row) of posp/sexpp written exactly once (verified).
// ---------------------------------------------------------------------------
__global__ __launch_bounds__(256, 2) void simstat_tri(const f16* __restrict__ nfh,
                                                      float* __restrict__ posp,
                                                      float* __restrict__ sexpp) {
    __shared__ __align__(16) char smem[65536];   // 2 x 32KB dbuf

    const int t    = threadIdx.x;
    const int w    = t >> 6;
    const int lane = t & 63;
    const int lr   = lane & 15;
    const int lg   = lane >> 4;
    const int rowbase = 64 * (w >> 1);
    const int colbase = 64 * (w & 1);

    // stage mapping (loop-invariant): 4 waves x 8KB = 32KB tile
    int goffs[8], dbase[8];
#pragma unroll
    for (int i = 0; i < 8; ++i) {
        const int base = w * 8192 + i * 1024;
        const int d    = base + lane * 16;
        const int sr   = d >> 8;            // dest row 0..127
        const int slot = (d >> 4) & 15;
        const int kc   = slot ^ (sr & 15);  // involution
        goffs[i] = sr * NFD + kc * 8;
        dbase[i] = base;
    }
    int rbo[4], koff[4];
#pragma unroll
    for (int fb = 0; fb < 4; ++fb) rbo[fb] = (colbase + 16 * fb + lr) * 256;
#pragma unroll
    for (int ks = 0; ks < 4; ++ks) koff[ks] = (((ks << 2) + lg) ^ lr) << 4;

    int rt, ct;
    decode_pair(PPB * blockIdx.x, rt, ct);

    // stage B for pair 0
    {
        const f16* g0 = nfh + (size_t)(ct * 128) * NFD;
#pragma unroll
        for (int j = 0; j < 8; ++j) gl16(g0 + goffs[j], smem + dbase[j]);
    }

    f16x8 ah[4][4];
#define LOADA(rt_)                                                            \
    {                                                                         \
        _Pragma("unroll")                                                     \
        for (int ks = 0; ks < 4; ++ks)                                        \
            _Pragma("unroll")                                                 \
            for (int fa = 0; fa < 4; ++fa)                                    \
                ah[ks][fa] = *reinterpret_cast<const f16x8*>(                 \
                    nfh + (size_t)((rt_)*128 + rowbase + 16 * fa + lr) * NFD  \
                        + 32 * ks + 8 * lg);                                  \
    }
    LOADA(rt);
    int cur_rt = rt;
    __syncthreads();   // pair-0 stage + A complete

    const float K2 = 1.44269504089f / 0.07f;   // log2(e)/tau
    const float invtau = 1.0f / 0.07f;

#pragma unroll 1
    for (int i = 0; i < PPB; ++i) {
        // A-reload first (rare; block-uniform branch)
        if (rt != cur_rt) { LOADA(rt); cur_rt = rt; }

        // advance + stage next pair's B (issued after A-loads: vmcnt for A
        // completes without draining these)
        int nrt = rt, nct = ct;
        if (i < PPB - 1) {
            nct = ct + 1;
            if (nct == 64) { nrt = rt + 1; nct = nrt; }
            char* nb = smem + ((i + 1) & 1) * 32768;
            const f16* gn = nfh + (size_t)(nct * 128) * NFD;
#pragma unroll
            for (int j = 0; j < 8; ++j) gl16(gn + goffs[j], nb + dbase[j]);
        }

        const char* buf = smem + (i & 1) * 32768;
        const bool same = ((rt >= 32) == (ct >= 32));
        const bool diag = (rt == ct);

        f32x4 acc[4][4];
#pragma unroll
        for (int fa = 0; fa < 4; ++fa)
#pragma unroll
            for (int fb = 0; fb < 4; ++fb) {
                f32x4 z = {0.0f, 0.0f, 0.0f, 0.0f};
                acc[fa][fb] = z;
            }

#define LOADB(ks_, B_)                                                        \
    {                                                                         \
        _Pragma("unroll")                                                     \
        for (int fb = 0; fb < 4; ++fb)                                        \
            B_[fb] = *(const f16x8*)(buf + rbo[fb] + koff[ks_]);              \
    }
#define MFMAS(ks_, B_)                                                        \
    {                                                                         \
        __builtin_amdgcn_s_setprio(1);                                        \
        _Pragma("unroll")                                                     \
        for (int fb = 0; fb < 4; ++fb)                                        \
            _Pragma("unroll")                                                 \
            for (int fa = 0; fa < 4; ++fa)                                    \
                acc[fa][fb] = __builtin_amdgcn_mfma_f32_16x16x32_f16(ah[ks_][fa], B_[fb], acc[fa][fb], 0, 0, 0); \
        __builtin_amdgcn_s_setprio(0);                                        \
    }
        {
            f16x8 b0[4], b1[4];
            LOADB(0, b0);
            LOADB(1, b1);
            MFMAS(0, b0);
            LOADB(2, b0);
            MFMAS(1, b1);
            LOADB(3, b1);
            MFMAS(2, b0);
            MFMAS(3, b1);
        }
#undef LOADB
#undef MFMAS

        // ---- fold; C/D: col=lane&15, row=4*lg+reg (m89-verified) ----
        float rstat[4][4], cstat[4];
#pragma unroll
        for (int fa = 0; fa < 4; ++fa)
#pragma unroll
            for (int r = 0; r < 4; ++r) rstat[fa][r] = same ? -3.0e38f : 0.0f;
#pragma unroll
        for (int fb = 0; fb < 4; ++fb) cstat[fb] = same ? -3.0e38f : 0.0f;

        if (same) {
#pragma unroll
            for (int fa = 0; fa < 4; ++fa)
#pragma unroll
                for (int fb = 0; fb < 4; ++fb)
#pragma unroll
                    for (int r = 0; r < 4; ++r) {
                        const float v = acc[fa][fb][r];
                        if (diag) {
                            const int grow = rowbase + 16 * fa + 4 * lg + r;
                            const int gcol = colbase + 16 * fb + lr;
                            if (grow != gcol) rstat[fa][r] = fmaxf(rstat[fa][r], v);
                        } else {
                            rstat[fa][r] = fmaxf(rstat[fa][r], v);
                            cstat[fb]    = fmaxf(cstat[fb], v);
                        }
                    }
        } else {
#pragma unroll
            for (int fa = 0; fa < 4; ++fa)
#pragma unroll
                for (int fb = 0; fb < 4; ++fb)
#pragma unroll
                    for (int r = 0; r < 4; ++r) {
                        const float e = exp2f(acc[fa][fb][r] * K2);  // once
                        rstat[fa][r] += e;
                        cstat[fb]    += e;
                    }
        }

        // rows: reduce over lr bits; direct write, slice 2*(ct&31)+(w&1)
#pragma unroll
        for (int m = 1; m <= 8; m <<= 1)
#pragma unroll
            for (int fa = 0; fa < 4; ++fa)
#pragma unroll
                for (int r = 0; r < 4; ++r) {
                    const float o = __shfl_xor(rstat[fa][r], m, 64);
                    rstat[fa][r] = same ? fmaxf(rstat[fa][r], o) : (rstat[fa][r] + o);
                }
        if (lr == 0) {
            float* dst = (same ? posp : sexpp) +
                         (size_t)(2 * (ct & 31) + (w & 1)) * NBTOT + rt * 128 + rowbase;
#pragma unroll
            for (int fa = 0; fa < 4; ++fa)
#pragma unroll
                for (int r = 0; r < 4; ++r)
                    dst[16 * fa + 4 * lg + r] = same ? rstat[fa][r] * invtau : rstat[fa][r];
        }
        // cols: reduce over lg bits; direct write, slice 2*(rt&31)+(w>>1)
#pragma unroll
        for (int m = 16; m <= 32; m <<= 1)
#pragma unroll
            for (int fb = 0; fb < 4; ++fb) {
                const float o = __shfl_xor(cstat[fb], m, 64);
                cstat[fb] = same ? fmaxf(cstat[fb], o) : (cstat[fb] + o);
            }
        if (!diag && lg == 0) {
            float* dst = (same ? posp : sexpp) +
                         (size_t)(2 * (rt & 31) + (w >> 1)) * NBTOT + ct * 128 + colbase;
#pragma unroll
            for (int fb = 0; fb < 4; ++fb)
                dst[16 * fb + lr] = same ? cstat[fb] * invtau : cstat[fb];
        }

        rt = nrt; ct = nct;
        __syncthreads();   // next buf staged; all waves done with current buf
    }
#undef LOADA
}

// ---------------------------------------------------------------------------
// Kernel 3a: per-row loss partials, 32 blocks. loss_i = log1p(S*exp(-pos))
// ---------------------------------------------------------------------------
__global__ void loss_part(const float* __restrict__ posp, const float* __restrict__ sexpp,
                          float* __restrict__ partial) {
    const int i = blockIdx.x * 256 + threadIdx.x;
    float pv = -3.0e38f, se = 0.0f;
#pragma unroll 8
    for (int s = 0; s < NSL; ++s) {
        pv = fmaxf(pv, posp[(size_t)s * NBTOT + i]);
        se += sexpp[(size_t)s * NBTOT + i];
    }
    float l = log1pf(se * __expf(-pv));
#pragma unroll
    for (int m = 32; m >= 1; m >>= 1) l += __shfl_xor(l, m, 64);
    __shared__ float part[4];
    if ((threadIdx.x & 63) == 0) part[threadIdx.x >> 6] = l;
    __syncthreads();
    if (threadIdx.x == 0)
        partial[blockIdx.x] = part[0] + part[1] + part[2] + part[3];
}

// Kernel 3b: final combine (1 wave).
__global__ void loss_final(const float* __restrict__ partial, float* __restrict__ out) {
    const int t = threadIdx.x;
    float s = (t < 32) ? partial[t] : 0.0f;
#pragma unroll
    for (int m = 32; m >= 1; m >>= 1) s += __shfl_xor(s, m, 64);
    if (t == 0) out[0] = s / (float)NBTOT;
}

// ---------------------------------------------------------------------------
extern "C" void kernel_launch(void* const* d_in, const int* in_sizes, int n_in,
                              void* d_out, int out_size, void* d_ws, size_t ws_size,
                              hipStream_t stream) {
    const float* f1 = (const float*)d_in[0];
    const float* f2 = (const float*)d_in[1];

    f16*   nfh     = (f16*)d_ws;                          // 2 MB
    float* posp    = (float*)(nfh + (size_t)NBTOT * NFD); // 64*8192 f32 = 2 MB
    float* sexpp   = posp + (size_t)NSL * NBTOT;          // 2 MB
    float* partial = sexpp + (size_t)NSL * NBTOT;         // 32 f32

    norm_k<<<NBTOT / 4, 256, 0, stream>>>(f1, f2, nfh);
    simstat_tri<<<NBLK, 256, 0, stream>>>(nfh, posp, sexpp);
    loss_part<<<NBTOT / 256, 256, 0, stream>>>(posp, sexpp, partial);
    loss_final<<<1, 64, 0, stream>>>(partial, (float*)d_out);
}

// Round 14
// 46.456 us; speedup vs baseline: 1.4028x; 1.1575x over previous
//
#include <hip/hip_runtime.h>
#include <math.h>
#include <stdint.h>

#define NB1    4096
#define NBTOT  8192
#define NFD    128
#define NSL    16            // partial slices per class

typedef __attribute__((ext_vector_type(8))) _Float16 f16x8;
typedef __attribute__((ext_vector_type(4))) float f32x4;
typedef _Float16 f16;

// async 16B global->LDS; lds base wave-uniform, HW adds lane*16
__device__ __forceinline__ void gl16(const f16* g, char* l) {
    __builtin_amdgcn_global_load_lds(
        (const __attribute__((address_space(1))) unsigned int*)g,
        (__attribute__((address_space(3))) unsigned int*)l,
        16, 0, 0);
}

// ---------------------------------------------------------------------------
// Kernel 1: row L2-normalize -> fp16 (validated R8: loss err ~0.015 << 0.0925)
// ---------------------------------------------------------------------------
__global__ void norm_k(const float* __restrict__ f1, const float* __restrict__ f2,
                       f16* __restrict__ nfh) {
    const int w = threadIdx.x >> 6, lane = threadIdx.x & 63;
    const int row = blockIdx.x * 4 + w;
    const float* src = (row < NB1) ? (f1 + (size_t)row * NFD)
                                   : (f2 + (size_t)(row - NB1) * NFD);
    const float2 v = *reinterpret_cast<const float2*>(src + 2 * lane);
    float s = v.x * v.x + v.y * v.y;
#pragma unroll
    for (int m = 32; m >= 1; m >>= 1) s += __shfl_xor(s, m, 64);
    const float inv = 1.0f / fmaxf(sqrtf(s), 1e-12f);
    const f16 h0 = (f16)(v.x * inv);
    const f16 h1 = (f16)(v.y * inv);
    const unsigned pack = (unsigned)__builtin_bit_cast(unsigned short, h0) |
                          ((unsigned)__builtin_bit_cast(unsigned short, h1) << 16);
    ((unsigned*)(nfh + (size_t)row * NFD))[lane] = pack;
}

// ---------------------------------------------------------------------------
// Kernel 2: ONE-BARRIER sim-stats. Grid (32 col-slices x 64 row-tiles) = 2048
// blocks, 2 resident/CU (64KB LDS). Block = 128 rows x 256 cols.
// Stage the WHOLE 256x128 B-slice (64KB) once -> single __syncthreads ->
// waves free-run over 4 col-tiles with zero further syncs (desynced pipes).
// 4 waves; wave w owns rows 32w..32w+31 (fa=2, private) and ALL cols (fb=4),
// so row-stats are wave-private -> direct global write, slice s&15, no
// cross-wave combine. A-frags in regs. 4-bit XOR swizzle (R8-proven, 0 confl).
// Diag: only blocks with s == rt>>1 (uniform branch).
// ---------------------------------------------------------------------------
__global__ __launch_bounds__(256, 2) void simstat_k(const f16* __restrict__ nfh,
                                                    float* __restrict__ posp,
                                                    float* __restrict__ sexpp) {
    __shared__ __align__(16) char smem[65536];   // 256 cols x 256B, swizzled

    const int s    = blockIdx.x;          // col slice 0..31 (256 cols)
    const int rt   = blockIdx.y;          // row tile 0..63 (128 rows)
    const int col0 = s * 256;
    const int row0 = rt * 128;
    const bool same    = ((rt >= 32) == (s >= 16));
    const bool hasdiag = (s == (rt >> 1));

    const int t    = threadIdx.x;
    const int w    = t >> 6;
    const int lane = t & 63;
    const int lr   = lane & 15;
    const int lg   = lane >> 4;
    const int rowbase = 32 * w;

    // ---- stage entire B-slice (64KB), pre-swizzled source ----
    {
        const f16* g0 = nfh + (size_t)col0 * NFD;
#pragma unroll
        for (int i = 0; i < 16; ++i) {
            const int base = w * 16384 + i * 1024;
            const int d    = base + lane * 16;
            const int sr   = d >> 8;            // dest row 0..255
            const int slot = (d >> 4) & 15;
            const int kc   = slot ^ (sr & 15);  // involution
            gl16(g0 + sr * NFD + kc * 8, smem + base);
        }
    }

    // ---- A fragments -> registers (drained by the same barrier) ----
    f16x8 ah[4][2];
#pragma unroll
    for (int ks = 0; ks < 4; ++ks)
#pragma unroll
        for (int fa = 0; fa < 2; ++fa)
            ah[ks][fa] = *reinterpret_cast<const f16x8*>(
                nfh + (size_t)(row0 + rowbase + 16 * fa + lr) * NFD + 32 * ks + 8 * lg);

    int rbo[4], koff[4];
#pragma unroll
    for (int fb = 0; fb < 4; ++fb) rbo[fb] = (16 * fb + lr) * 256;
#pragma unroll
    for (int ks = 0; ks < 4; ++ks) koff[ks] = (((ks << 2) + lg) ^ lr) << 4;

    __syncthreads();   // THE only barrier: stage + A complete

    const float K2 = 1.44269504089f / 0.07f;   // log2(e)/tau
    const float invtau = 1.0f / 0.07f;
    float rstat[2][4];
#pragma unroll
    for (int fa = 0; fa < 2; ++fa)
#pragma unroll
        for (int r = 0; r < 4; ++r) rstat[fa][r] = same ? -3.0e38f : 0.0f;

#define LOADB(ks_, B_)                                                        \
    {                                                                         \
        _Pragma("unroll")                                                     \
        for (int fb = 0; fb < 4; ++fb)                                        \
            B_[fb] = *(const f16x8*)(buf + rbo[fb] + koff[ks_]);              \
    }
#define MFMAS(ks_, B_)                                                        \
    {                                                                         \
        __builtin_amdgcn_s_setprio(1);                                        \
        _Pragma("unroll")                                                     \
        for (int fb = 0; fb < 4; ++fb)                                        \
            _Pragma("unroll")                                                 \
            for (int fa = 0; fa < 2; ++fa)                                    \
                acc[fa][fb] = __builtin_amdgcn_mfma_f32_16x16x32_f16(ah[ks_][fa], B_[fb], acc[fa][fb], 0, 0, 0); \
        __builtin_amdgcn_s_setprio(0);                                        \
    }

#pragma unroll 1
    for (int ct = 0; ct < 4; ++ct) {
        const char* buf = smem + ct * 16384;

        f32x4 acc[2][4];
#pragma unroll
        for (int fa = 0; fa < 2; ++fa)
#pragma unroll
            for (int fb = 0; fb < 4; ++fb) {
                f32x4 z = {0.0f, 0.0f, 0.0f, 0.0f};
                acc[fa][fb] = z;
            }

        f16x8 b0[4], b1[4];
        LOADB(0, b0);
        LOADB(1, b1);
        MFMAS(0, b0);
        LOADB(2, b0);
        MFMAS(1, b1);
        LOADB(3, b1);
        MFMAS(2, b0);
        MFMAS(3, b1);

        // fold; C/D: col=lane&15, row=4*lg+reg (m89-verified)
        if (same) {
            if (hasdiag) {
#pragma unroll
                for (int fa = 0; fa < 2; ++fa)
#pragma unroll
                    for (int fb = 0; fb < 4; ++fb)
#pragma unroll
                        for (int r = 0; r < 4; ++r) {
                            const int grow = row0 + rowbase + 16 * fa + 4 * lg + r;
                            const int gcol = col0 + ct * 64 + 16 * fb + lr;
                            if (grow != gcol)
                                rstat[fa][r] = fmaxf(rstat[fa][r], acc[fa][fb][r]);
                        }
            } else {
#pragma unroll
                for (int fa = 0; fa < 2; ++fa)
#pragma unroll
                    for (int fb = 0; fb < 4; ++fb)
#pragma unroll
                        for (int r = 0; r < 4; ++r)
                            rstat[fa][r] = fmaxf(rstat[fa][r], acc[fa][fb][r]);
            }
        } else {
#pragma unroll
            for (int fa = 0; fa < 2; ++fa)
#pragma unroll
                for (int fb = 0; fb < 4; ++fb)
#pragma unroll
                    for (int r = 0; r < 4; ++r)
                        rstat[fa][r] += exp2f(acc[fa][fb][r] * K2);
        }
    }
#undef LOADB
#undef MFMAS

    // reduce over the 16 cols held across lr (lane bits 0..3)
#pragma unroll
    for (int m = 1; m <= 8; m <<= 1)
#pragma unroll
        for (int fa = 0; fa < 2; ++fa)
#pragma unroll
            for (int r = 0; r < 4; ++r) {
                const float o = __shfl_xor(rstat[fa][r], m, 64);
                rstat[fa][r] = same ? fmaxf(rstat[fa][r], o) : (rstat[fa][r] + o);
            }

    // wave-private rows -> direct write, slice s&15 (each slot written once)
    if (lr == 0) {
        float* dst = (same ? posp : sexpp) +
                     (size_t)(s & 15) * NBTOT + row0 + rowbase;
#pragma unroll
        for (int fa = 0; fa < 2; ++fa)
#pragma unroll
            for (int r = 0; r < 4; ++r)
                dst[16 * fa + 4 * lg + r] = same ? rstat[fa][r] * invtau : rstat[fa][r];
    }
}

// ---------------------------------------------------------------------------
// Kernel 3a: per-row loss partials, 32 blocks. loss_i = log1p(S*exp(-pos))
// ---------------------------------------------------------------------------
__global__ void loss_part(const float* __restrict__ posp, const float* __restrict__ sexpp,
                          float* __restrict__ partial) {
    const int i = blockIdx.x * 256 + threadIdx.x;
    float pv = -3.0e38f, se = 0.0f;
#pragma unroll 4
    for (int s = 0; s < NSL; ++s) {
        pv = fmaxf(pv, posp[(size_t)s * NBTOT + i]);
        se += sexpp[(size_t)s * NBTOT + i];
    }
    float l = log1pf(se * __expf(-pv));
#pragma unroll
    for (int m = 32; m >= 1; m >>= 1) l += __shfl_xor(l, m, 64);
    __shared__ float part[4];
    if ((threadIdx.x & 63) == 0) part[threadIdx.x >> 6] = l;
    __syncthreads();
    if (threadIdx.x == 0)
        partial[blockIdx.x] = part[0] + part[1] + part[2] + part[3];
}

// Kernel 3b: final combine (1 wave).
__global__ void loss_final(const float* __restrict__ partial, float* __restrict__ out) {
    const int t = threadIdx.x;
    float s = (t < 32) ? partial[t] : 0.0f;
#pragma unroll
    for (int m = 32; m >= 1; m >>= 1) s += __shfl_xor(s, m, 64);
    if (t == 0) out[0] = s / (float)NBTOT;
}

// ---------------------------------------------------------------------------
extern "C" void kernel_launch(void* const* d_in, const int* in_sizes, int n_in,
                              void* d_out, int out_size, void* d_ws, size_t ws_size,
                              hipStream_t stream) {
    const float* f1 = (const float*)d_in[0];
    const float* f2 = (const float*)d_in[1];

    f16*   nfh     = (f16*)d_ws;                          // 2 MB
    float* posp    = (float*)(nfh + (size_t)NBTOT * NFD); // 16*8192 f32
    float* sexpp   = posp + (size_t)NSL * NBTOT;          // 16*8192 f32
    float* partial = sexpp + (size_t)NSL * NBTOT;         // 32 f32

    norm_k<<<NBTOT / 4, 256, 0, stream>>>(f1, f2, nfh);
    simstat_k<<<dim3(32, 64), 256, 0, stream>>>(nfh, posp, sexpp);
    loss_part<<<NBTOT / 256, 256, 0, stream>>>(posp, sexpp, partial);
    loss_final<<<1, 64, 0, stream>>>(partial, (float*)d_out);
}